// Round 1
// baseline (284.492 us; speedup 1.0000x reference)
//
#include <hip/hip_runtime.h>
#include <math.h>

#define B_     1024
#define T_     80
#define D_     512
#define C_     78      // VOCAB+1
#define PRED_  30
#define BLANK_ 77
#define NKK    16      // 512 / 32
#define FRAG   512     // ushorts per fragment block (64 lanes * 8 halves)
#define PLANE_STRIDE (5 * NKK * FRAG)   // 40960 ushorts per plane

typedef __attribute__((ext_vector_type(8))) _Float16 f16x8;
typedef __attribute__((ext_vector_type(4))) float    f32x4;

// Split W [512,78] fp32 into two f16 planes (w1 = rnd(w), w2 = rnd(w - w1)),
// fragment-linear: [plane][ct][kk][lane][j] -> main-loop B load = base + lane*16B.
__global__ __launch_bounds__(256) void prep_w(const float* __restrict__ W,
                                              ushort* __restrict__ Wf) {
    int i = blockIdx.x * 256 + threadIdx.x;
    if (i >= 2 * PLANE_STRIDE) return;
    int j    = i & 7;
    int lane = (i >> 3) & 63;
    int kk   = (i >> 9) & 15;
    int rest = i >> 13;          // plane*5 + ct
    int ct   = rest % 5;
    int plane = rest / 5;
    int q = lane >> 4, n = lane & 15;
    int k = kk * 32 + q * 8 + j;
    int c = ct * 16 + n;
    float v = (c < C_) ? W[k * C_ + c] : 0.f;
    _Float16 h1 = (_Float16)v;
    union { _Float16 h; ushort u; } cv;
    cv.h = (plane == 0) ? h1 : (_Float16)(v - (float)h1);
    Wf[i] = cv.u;
}

// Block = 320 threads (5 waves) = ONE batch element (80 rows). Wave w owns the
// 16-row MFMA tile [w*16, w*16+16), all 78 (padded->80) cols, K=512.
// A: DIRECT global->register loads (no LDS, no K-loop barriers). Each lane
// reads its own 32 contiguous bytes per K-slice: A[row=n][kk*32 + q*8 .. +8].
// B: fragment-linear Wf, L2-resident. C/D: col=lane&15, row=(lane>>4)*4+reg.
// f32 emulated as f16-split with 3 MFMAs (a1b1 + a2b1 + a1b2; a2b2 ~1e-6).
__global__ __launch_bounds__(320, 4) void gemm_ctc(
    const float* __restrict__ feat,   // [81920, 512] fp32
    const ushort* __restrict__ Wf,    // f16 split planes, fragment-linear
    const float* __restrict__ bias,   // [78] fp32
    float* __restrict__ probs,        // [81920, 78] fp32
    float* __restrict__ lab)          // [1024, 30] fp32
{
    __shared__ int best_s[T_];

    const int tid  = threadIdx.x;
    const int w    = tid >> 6;
    const int lane = tid & 63;
    const int q    = lane >> 4;
    const int n    = lane & 15;

    f32x4 acc[5];
    #pragma unroll
    for (int ct = 0; ct < 5; ++ct)
        acc[ct] = (f32x4){0.f, 0.f, 0.f, 0.f};

    // this lane's A row: batch elem blockIdx.x, time = w*16 + n
    const float*  Ap  = feat + ((size_t)blockIdx.x * T_ + w * 16 + n) * D_ + q * 8;
    const ushort* bp0 = Wf + lane * 8;

    float4 c0 = *(const float4*)(Ap);
    float4 c1 = *(const float4*)(Ap + 4);

    #pragma unroll 2
    for (int kk = 0; kk < NKK; ++kk) {
        // depth-1 prefetch (clamped on last iter: redundant L1-hit, no OOB)
        const int nk = (kk < NKK - 1) ? kk + 1 : NKK - 1;
        float4 n0 = *(const float4*)(Ap + nk * 32);
        float4 n1 = *(const float4*)(Ap + nk * 32 + 4);

        float v[8] = {c0.x, c0.y, c0.z, c0.w, c1.x, c1.y, c1.z, c1.w};
        f16x8 a1f, a2f;
        #pragma unroll
        for (int j = 0; j < 8; ++j) {
            _Float16 h = (_Float16)v[j];
            a1f[j] = h;
            a2f[j] = (_Float16)(v[j] - (float)h);
        }

        const ushort* bpk = bp0 + kk * FRAG;
        #pragma unroll
        for (int ct = 0; ct < 5; ++ct) {
            const ushort* bp = bpk + ct * (NKK * FRAG);
            f16x8 b1 = *(const f16x8*)bp;
            f16x8 b2 = *(const f16x8*)(bp + PLANE_STRIDE);
            acc[ct] = __builtin_amdgcn_mfma_f32_16x16x32_f16(a1f, b1, acc[ct], 0, 0, 0);
            acc[ct] = __builtin_amdgcn_mfma_f32_16x16x32_f16(a2f, b1, acc[ct], 0, 0, 0);
            acc[ct] = __builtin_amdgcn_mfma_f32_16x16x32_f16(a1f, b2, acc[ct], 0, 0, 0);
        }
        c0 = n0; c1 = n1;
    }

    // ---- epilogue: bias + argmax + softmax + nontemporal stores ----
    float x[5][4];
    #pragma unroll
    for (int ct = 0; ct < 5; ++ct) {
        int c = ct * 16 + n;
        bool valid = (c < C_);
        float bv = valid ? bias[c] : 0.f;
        #pragma unroll
        for (int r = 0; r < 4; ++r)
            x[ct][r] = valid ? (acc[ct][r] + bv) : -INFINITY;
    }
    float av[4]; int ai[4];
    #pragma unroll
    for (int r = 0; r < 4; ++r) {
        av[r] = x[0][r]; ai[r] = n;
        #pragma unroll
        for (int ct = 1; ct < 5; ++ct) {
            int c = ct * 16 + n;
            if (x[ct][r] > av[r]) { av[r] = x[ct][r]; ai[r] = c; }
        }
    }
    #pragma unroll
    for (int off = 8; off >= 1; off >>= 1) {
        #pragma unroll
        for (int r = 0; r < 4; ++r) {
            float ov = __shfl_xor(av[r], off, 16);
            int   oi = __shfl_xor(ai[r], off, 16);
            if (ov > av[r] || (ov == av[r] && oi < ai[r])) { av[r] = ov; ai[r] = oi; }
        }
    }
    float s[4] = {0.f, 0.f, 0.f, 0.f};
    #pragma unroll
    for (int ct = 0; ct < 5; ++ct)
        #pragma unroll
        for (int r = 0; r < 4; ++r) {
            x[ct][r] = __expf(x[ct][r] - av[r]);   // -INF -> 0
            s[r] += x[ct][r];
        }
    #pragma unroll
    for (int off = 8; off >= 1; off >>= 1)
        #pragma unroll
        for (int r = 0; r < 4; ++r) s[r] += __shfl_xor(s[r], off, 16);

    // wave w covers global rows blk*80 + w*16 + (q*4 + r)
    const size_t growb = (size_t)blockIdx.x * T_ + w * 16 + q * 4;
    #pragma unroll
    for (int r = 0; r < 4; ++r) {
        float inv = 1.f / s[r];
        float* op = probs + (growb + r) * C_;
        #pragma unroll
        for (int ct = 0; ct < 5; ++ct) {
            int c = ct * 16 + n;
            if (c < C_) __builtin_nontemporal_store(x[ct][r] * inv, op + c);
        }
    }
    if (n == 0) {
        int rl = w * 16 + q * 4;   // time index within this batch element
        #pragma unroll
        for (int r = 0; r < 4; ++r)
            best_s[rl + r] = ai[r];
    }
    __syncthreads();

    // in-block CTC greedy decode (1 batch element)
    if (tid == 0) {
        float* op = lab + (size_t)blockIdx.x * PRED_;
        int prev = -1, pos = 0;
        for (int t2 = 0; t2 < T_; ++t2) {
            int v = best_s[t2];
            if (v != BLANK_ && v != prev) {
                if (pos < PRED_) op[pos] = (float)v;
                ++pos;
            }
            prev = v;
        }
        for (int i2 = (pos < PRED_ ? pos : PRED_); i2 < PRED_; ++i2) op[i2] = -1.f;
    }
}

extern "C" void kernel_launch(void* const* d_in, const int* in_sizes, int n_in,
                              void* d_out, int out_size, void* d_ws, size_t ws_size,
                              hipStream_t stream) {
    const float* feat = (const float*)d_in[0];   // fp32 [1024,80,512]
    const float* W    = (const float*)d_in[1];   // fp32 [512,78]
    const float* bias = (const float*)d_in[2];   // fp32 [78]
    // d_in[3]=y, d_in[4]=times : unused
    float*  probs = (float*)d_out;
    float*  lab   = probs + (size_t)B_ * T_ * C_;
    ushort* Wf    = (ushort*)d_ws;               // 163840 B scratch

    hipLaunchKernelGGL(prep_w, dim3(320), dim3(256), 0, stream, W, Wf);
    hipLaunchKernelGGL(gemm_ctc, dim3(B_), dim3(320), 0, stream,
                       feat, Wf, bias, probs, lab);
}